// Round 5
// baseline (490.570 us; speedup 1.0000x reference)
//
#include <hip/hip_runtime.h>
#include <hip/hip_bf16.h>

#define NN 4096
#define EE 2048
#define RR 4
#define FF 128
#define HDD 256

typedef __attribute__((ext_vector_type(4))) float floatx4;
typedef __attribute__((ext_vector_type(8))) __bf16 bf16x8;

#define AS1 __attribute__((address_space(1)))
#define AS3 __attribute__((address_space(3)))

__device__ __forceinline__ void async16(const void* g, void* l) {
  __builtin_amdgcn_global_load_lds((const AS1 void*)(unsigned long long)(g),
                                   (AS3 void*)(unsigned int)(unsigned long long)(l),
                                   16, 0, 0);
}

__device__ inline unsigned short f2b(float x) {
  unsigned int u = __float_as_uint(x);
  unsigned int r = u + 0x7fffu + ((u >> 16) & 1u);
  return (unsigned short)(r >> 16);
}
__device__ inline float b2f(unsigned short u) { return __uint_as_float((unsigned int)u << 16); }

__device__ inline float rel_w(const float* rel, int r) {
  float m = fmaxf(fmaxf(rel[0], rel[1]), fmaxf(rel[2], rel[3]));
  float s = 0.f;
#pragma unroll
  for (int i = 0; i < RR; i++) s += expf(rel[i] - m);
  return expf(rel[r] - m) / s;
}

// ==== prep1: fused {dvmask | wprep | zero(de,cs)} by block range ====
__global__ void k_prep1(const float* __restrict__ H, const float* __restrict__ rel,
                        const float* __restrict__ W1, const float* __restrict__ W2,
                        const float* __restrict__ W3, const float* __restrict__ imp,
                        float* __restrict__ dvs, unsigned long long* __restrict__ mask,
                        unsigned short* __restrict__ W1catT, unsigned short* __restrict__ W2T,
                        unsigned short* __restrict__ W3T, float* __restrict__ de, float* __restrict__ cs) {
  int b = blockIdx.x;
  if (b < 4096) {
    int wave = (b << 2) | (threadIdx.x >> 6);  // = r*NN + n
    int lane = threadIdx.x & 63;
    int r = wave >> 12;
    const float* row = H + (size_t)wave * EE;
    unsigned long long* mrow = mask + (size_t)wave * (EE / 64);
    float s = 0.f;
    for (int j = 0; j < EE / 64; j++) {
      float h = row[j * 64 + lane];
      s += h;
      unsigned long long m = __ballot(h != 0.0f);
      if (lane == 0) mrow[j] = m;
    }
    for (int off = 32; off; off >>= 1) s += __shfl_down(s, off);
    if (lane == 0) {
      float rwr = rel_w(rel, r);
      dvs[wave] = rwr * rsqrtf(rwr * s + 1e-8f);
    }
  } else if (b < 4096 + 2048) {
    int idx = (b - 4096) * 256 + threadIdx.x;
    if (idx < RR * FF * HDD) {
      int o = idx % HDD, f = (idx / HDD) % FF, r = idx / (HDD * FF);
      float sg = 1.0f / (1.0f + expf(-imp[r]));
      W1catT[(size_t)o * (RR * FF) + r * FF + f] = f2b(sg * W1[((size_t)r * FF + f) * HDD + o]);
    } else if (idx < RR * FF * HDD + RR * HDD * HDD) {
      int j = idx - RR * FF * HDD;
      int c = j % HDD, o = (j / HDD) % HDD, r = j / (HDD * HDD);
      float sg = 1.0f / (1.0f + expf(-imp[RR + r]));
      W2T[j] = f2b(sg * W2[((size_t)r * HDD + c) * HDD + o]);
    } else {
      int j = idx - RR * FF * HDD - RR * HDD * HDD;
      int c = j % HDD, o = (j / HDD) % FF, r = j / (HDD * FF);
      float sg = 1.0f / (1.0f + expf(-imp[2 * RR + r]));
      W3T[j] = f2b(sg * W3[((size_t)r * HDD + c) * FF + o]);
    }
  } else {
    int i = (b - 6144) * 256 + threadIdx.x;
    if (i < RR * EE) de[i] = 0.f;
    else if (i < RR * EE + 2 * HDD) cs[i - RR * EE] = 0.f;
  }
}

// ==== prep2: fused {maskT (bit-transpose + de counts) | cvtTs (X -> dv-scaled bf16 [r][f][n])} ====
__global__ void k_prep2(const unsigned long long* __restrict__ m1, unsigned long long* __restrict__ m2,
                        float* __restrict__ de, const float* __restrict__ X,
                        const float* __restrict__ dvs, unsigned short* __restrict__ XdvT) {
  __shared__ unsigned long long w[64 * 33];
  __shared__ unsigned short tile[64][65];
  int t = threadIdx.x;
  if (blockIdx.x < 256) {
    int r = blockIdx.x >> 6;
    int n0 = (blockIdx.x & 63) << 6;
    const unsigned long long* src = m1 + ((size_t)r * NN + n0) * 32;
#pragma unroll
    for (int i = 0; i < 8; i++) {
      int idx = t + i * 256;
      int n = idx >> 5, W = idx & 31;
      w[n * 33 + W] = src[idx];
    }
    __syncthreads();
    int wid = t >> 6, lane = t & 63;
    int v = n0 >> 6;
#pragma unroll
    for (int Wi = 0; Wi < 8; Wi++) {
      int W = wid * 8 + Wi;
      unsigned long long myw = w[lane * 33 + W];
      unsigned long long out = 0;
      for (int b = 0; b < 64; b++) {
        unsigned long long mm = __ballot(((myw >> b) & 1ULL) != 0);
        if (lane == b) out = mm;
      }
      m2[((size_t)r * EE + W * 64 + lane) * 64 + v] = out;
      atomicAdd(&de[r * EE + W * 64 + lane], (float)__popcll(out));
    }
  } else {
    int idx = blockIdx.x - 256;
    int c0 = (idx & 1) * 64, m0 = ((idx >> 1) & 63) * 64, r = idx >> 7;
    int tr = t >> 4, tc = t & 15;
#pragma unroll
    for (int i = 0; i < 4; i++) {
      int m = m0 + tr + 16 * i;
      float d = dvs[(size_t)r * NN + m];
      float4 v = *(const float4*)(X + (size_t)m * FF + c0 + tc * 4);
      tile[tr + 16 * i][tc * 4 + 0] = f2b(v.x * d);
      tile[tr + 16 * i][tc * 4 + 1] = f2b(v.y * d);
      tile[tr + 16 * i][tc * 4 + 2] = f2b(v.z * d);
      tile[tr + 16 * i][tc * 4 + 3] = f2b(v.w * d);
    }
    __syncthreads();
    unsigned short* db = XdvT + (size_t)r * FF * NN;
#pragma unroll
    for (int i = 0; i < 4; i++) {
      int c = c0 + tr + 16 * i;
      ushort4 v;
      v.x = tile[tc * 4 + 0][tr + 16 * i];
      v.y = tile[tc * 4 + 1][tr + 16 * i];
      v.z = tile[tc * 4 + 2][tr + 16 * i];
      v.w = tile[tc * 4 + 3][tr + 16 * i];
      *(ushort4*)(db + (size_t)c * NN + m0 + tc * 4) = v;
    }
  }
}

// ---------------- MFMA GEMM, 128x128 tile, BK=64, single-barrier dbuf pipeline ----------------
// DEC: 0 none, 1 = A decoded from bitmask, 2 = B decoded.
// FLAT (requires DEC==1): k spans r*EE+e over mask1 (hardcoded layout [r*NN+n][32 u64]);
//   scatter value = bf16(dvs_[r*NN + row]) selected per k-step from a packed u64.
// Non-FLAT decode: mask rows at dm + (zr*drow_rs + rowbase + row)*dnw, scatter 1.0.
// Epilogue: optional generic f32 col-scale cscale[zr*cs_rs+col]; optional de-based scale
//   1/(rel_w(rel,zr)*de[zr*EE+idx]+eps) on rows (derow) or cols (decol).
template <int DEC, int FLAT>
__global__ __launch_bounds__(256) void k_gemm3(
    const unsigned short* __restrict__ A, const unsigned short* __restrict__ BT,
    int K, int SK, int lda, int ldb, long a_rs, long b_rs,
    unsigned short* __restrict__ P, long c_ps, long c_rs, int ldc,
    const unsigned long long* __restrict__ dm, int dnw, long drow_rs,
    const float* __restrict__ dvs_,
    const float* __restrict__ cscale, long cs_rs,
    const float* __restrict__ derow, const float* __restrict__ decol,
    const float* __restrict__ rel) {
  __shared__ unsigned short Al[2][128 * 64];
  __shared__ unsigned short Bl[2][128 * 64];
  int tid = threadIdx.x, wid = tid >> 6, lane = tid & 63;
  int m0 = blockIdx.x << 7, n0 = blockIdx.y << 7;
  int z = blockIdx.z, zr = z / SK, kz = z - zr * SK;
  int Kc = K / SK;
  int r8 = lane >> 3, c8 = lane & 7;
  int swz = ((c8 ^ r8) << 3);
  const unsigned short* Ab = A + (DEC == 1 ? 0 : ((size_t)zr * a_rs + (size_t)m0 * lda + (size_t)kz * Kc));
  const unsigned short* Bb = BT + (DEC == 2 ? 0 : ((size_t)zr * b_rs + (size_t)n0 * ldb + (size_t)kz * Kc));
  const unsigned int* mrow = nullptr;
  int drow = 0, dhalf = 0, dsw = 0;
  unsigned long long dvpack = 0;
  if (DEC) {
    drow = tid >> 1; dhalf = tid & 1;
    dsw = drow & 7;
    if (FLAT) {
      int n = m0 + drow;
#pragma unroll
      for (int r4 = 0; r4 < 4; r4++)
        dvpack |= (unsigned long long)f2b(dvs_[(r4 << 12) + n]) << (r4 << 4);
    } else {
      long mrowOff = (long)zr * drow_rs + (DEC == 1 ? m0 : n0) + drow;
      mrow = (const unsigned int*)(dm + (size_t)mrowOff * dnw);
    }
  }
  auto stage = [&](int pb, int k0) {
    if (DEC != 1) {
#pragma unroll
      for (int t = 0; t < 4; t++) {
        int rbase = (wid << 5) + (t << 3);
        int row = rbase + r8;
        async16(Ab + (size_t)row * lda + k0 + swz, &Al[pb][rbase * 64 + lane * 8]);
      }
    }
    if (DEC != 2) {
#pragma unroll
      for (int t = 0; t < 4; t++) {
        int rbase = (wid << 5) + (t << 3);
        int row = rbase + r8;
        async16(Bb + (size_t)row * ldb + k0 + swz, &Bl[pb][rbase * 64 + lane * 8]);
      }
    }
    if (DEC) {
      unsigned short* Dl = (DEC == 1) ? &Al[pb][0] : &Bl[pb][0];
      long kglob = (long)kz * Kc + k0;
      unsigned int bits;
      unsigned short sval;
      if (FLAT) {
        int rr = (int)(kglob >> 11);
        int ew = (((int)kglob) & 2047) >> 5;
        bits = ((const unsigned int*)dm)[(((size_t)rr << 12) + (size_t)(m0 + drow)) * 64 + ew + dhalf];
        sval = (unsigned short)(dvpack >> ((rr & 3) << 4));
      } else {
        bits = mrow[(kglob >> 5) + dhalf];
        sval = (unsigned short)0x3F80;
      }
      uint4 zz = {0u, 0u, 0u, 0u};
#pragma unroll
      for (int g = 0; g < 4; g++) {
        int chunk = ((dhalf << 2) | g) ^ dsw;
        *(uint4*)&Dl[drow * 64 + chunk * 8] = zz;
      }
      while (bits) {
        int b = __builtin_ctz(bits);
        bits &= bits - 1;
        int kl = (dhalf << 5) + b;
        Dl[drow * 64 + (((kl >> 3) ^ dsw) << 3) + (kl & 7)] = sval;
      }
    }
  };
  int wm = (wid >> 1) << 6, wn = (wid & 1) << 6;
  int fm = lane & 15, quad = lane >> 4;
  int f7 = fm & 7;
  floatx4 acc[4][4];
#pragma unroll
  for (int i = 0; i < 4; i++)
#pragma unroll
    for (int j = 0; j < 4; j++) acc[i][j] = (floatx4){0.f, 0.f, 0.f, 0.f};
  auto compute = [&](int pb) {
#pragma unroll
    for (int ks = 0; ks < 2; ks++) {
      int kg = (ks << 2) | quad;
      int ko = ((kg ^ f7) << 3);
      bf16x8 a[4], b[4];
#pragma unroll
      for (int i = 0; i < 4; i++) {
        a[i] = *(const bf16x8*)&Al[pb][(wm + i * 16 + fm) * 64 + ko];
        b[i] = *(const bf16x8*)&Bl[pb][(wn + i * 16 + fm) * 64 + ko];
      }
#pragma unroll
      for (int i = 0; i < 4; i++)
#pragma unroll
        for (int j = 0; j < 4; j++)
          acc[i][j] = __builtin_amdgcn_mfma_f32_16x16x32_bf16(a[i], b[j], acc[i][j], 0, 0, 0);
    }
  };
  stage(0, 0);
  __syncthreads();
  for (int k0 = 0; k0 < Kc; k0 += 128) {   // all callers have Kc % 128 == 0
    if (k0 + 64 < Kc) stage(1, k0 + 64);
    compute(0);
    __syncthreads();
    if (k0 + 128 < Kc) stage(0, k0 + 128);
    compute(1);
    __syncthreads();
  }
  unsigned short* Cb = P + (size_t)kz * c_ps + (size_t)zr * c_rs;
  float rwr = (derow || decol) ? rel_w(rel, zr) : 0.f;
  float csc[4];
#pragma unroll
  for (int ni = 0; ni < 4; ni++) {
    int col = n0 + wn + ni * 16 + fm;
    float c = 1.0f;
    if (cscale) c = cscale[(size_t)zr * cs_rs + col];
    if (decol) c = 1.0f / (rwr * decol[(size_t)zr * EE + col] + 1e-8f);
    csc[ni] = c;
  }
#pragma unroll
  for (int mi = 0; mi < 4; mi++)
#pragma unroll
    for (int ni = 0; ni < 4; ni++)
#pragma unroll
      for (int v = 0; v < 4; v++) {
        int row = m0 + wm + mi * 16 + quad * 4 + v;
        int col = n0 + wn + ni * 16 + fm;
        float val = acc[mi][ni][v] * csc[ni];
        if (derow) val *= 1.0f / (rwr * derow[(size_t)zr * EE + row] + 1e-8f);
        Cb[(size_t)row * ldc + col] = f2b(val);
      }
}

// ---- reduce SK bf16 partials per zr -> bf16 out[zr][region] (pure sum; optional cs zeroing) ----
__global__ void k_red_b(const unsigned short* __restrict__ P, unsigned short* __restrict__ out,
                        int SK, long region, float* __restrict__ cszero) {
  if (cszero && blockIdx.x == 0 && blockIdx.y == 0) {
    cszero[threadIdx.x] = 0.f;
    cszero[threadIdx.x + 256] = 0.f;
  }
  long i = ((long)blockIdx.x * 256 + threadIdx.x) * 8;
  int zr = blockIdx.y;
  const unsigned short* p = P + (size_t)zr * SK * region + i;
  float s[8] = {0, 0, 0, 0, 0, 0, 0, 0};
  for (int k = 0; k < SK; k++) {
    const unsigned short* q = p + (size_t)k * region;
    ushort4 a = *(const ushort4*)q;
    ushort4 b = *(const ushort4*)(q + 4);
    s[0] += b2f(a.x); s[1] += b2f(a.y); s[2] += b2f(a.z); s[3] += b2f(a.w);
    s[4] += b2f(b.x); s[5] += b2f(b.y); s[6] += b2f(b.z); s[7] += b2f(b.w);
  }
  ushort4 o0, o1;
  o0.x = f2b(s[0]); o0.y = f2b(s[1]); o0.z = f2b(s[2]); o0.w = f2b(s[3]);
  o1.x = f2b(s[4]); o1.y = f2b(s[5]); o1.z = f2b(s[6]); o1.w = f2b(s[7]);
  unsigned short* d = out + (size_t)zr * region + i;
  *(ushort4*)d = o0;
  *(ushort4*)(d + 4) = o1;
}

// ---- reduce Z bf16 partials of [NN][HDD] -> convout f32 + fused BN stats ----
__global__ void k_redstats(const unsigned short* __restrict__ P, float* __restrict__ out,
                           float* __restrict__ cs, float* __restrict__ cs2, int Z) {
  __shared__ float sm[2][8][256];
  int cg = (threadIdx.x & 31) << 3;
  int rowt = threadIdx.x >> 5;
  int r0 = blockIdx.x * 32;
  float s[8] = {0, 0, 0, 0, 0, 0, 0, 0}, s2[8] = {0, 0, 0, 0, 0, 0, 0, 0};
  for (int j = 0; j < 4; j++) {
    int row = r0 + rowt * 4 + j;
    long idx = (long)row * HDD + cg;
    float acc[8] = {0, 0, 0, 0, 0, 0, 0, 0};
    for (int z = 0; z < Z; z++) {
      const unsigned short* p = P + (size_t)z * ((long)NN * HDD) + idx;
      ushort4 a = *(const ushort4*)p;
      ushort4 b = *(const ushort4*)(p + 4);
      acc[0] += b2f(a.x); acc[1] += b2f(a.y); acc[2] += b2f(a.z); acc[3] += b2f(a.w);
      acc[4] += b2f(b.x); acc[5] += b2f(b.y); acc[6] += b2f(b.z); acc[7] += b2f(b.w);
    }
    float4 o0 = {acc[0], acc[1], acc[2], acc[3]};
    float4 o1 = {acc[4], acc[5], acc[6], acc[7]};
    *(float4*)(out + idx) = o0;
    *(float4*)(out + idx + 4) = o1;
#pragma unroll
    for (int i = 0; i < 8; i++) { s[i] += acc[i]; s2[i] += acc[i] * acc[i]; }
  }
#pragma unroll
  for (int i = 0; i < 8; i++) { sm[0][rowt][cg + i] = s[i]; sm[1][rowt][cg + i] = s2[i]; }
  __syncthreads();
  int c = threadIdx.x;
  float a0 = 0, a1 = 0;
#pragma unroll
  for (int t = 0; t < 8; t++) { a0 += sm[0][t][c]; a1 += sm[1][t][c]; }
  atomicAdd(&cs[c], a0);
  atomicAdd(&cs2[c], a1);
}

// ---- final: d_out = X + b3 + sum_Z bf16 partials [Z][NN][FF] ----
__global__ void k_red_out(const unsigned short* __restrict__ P, const float* __restrict__ X,
                          const float* __restrict__ b3, float* __restrict__ out, int Z) {
  long i = ((long)blockIdx.x * 256 + threadIdx.x) * 4;
  int f = (int)(i & 127);
  float4 s = *(const float4*)(X + i);
  s.x += b3[f]; s.y += b3[f + 1]; s.z += b3[f + 2]; s.w += b3[f + 3];
  for (int z = 0; z < Z; z++) {
    ushort4 v = *(const ushort4*)(P + (size_t)z * (NN * FF) + i);
    s.x += b2f(v.x); s.y += b2f(v.y); s.z += b2f(v.z); s.w += b2f(v.w);
  }
  *(float4*)(out + i) = s;
}

// ---- BN (batch stats) -> LN -> ELU -> bf16 [NN][HDD] ----
__global__ void k_bnlnelu(const float* __restrict__ x, const float* __restrict__ cs, const float* __restrict__ cs2,
                          const float* __restrict__ bg, const float* __restrict__ bb,
                          const float* __restrict__ lg, const float* __restrict__ lb,
                          unsigned short* __restrict__ out) {
  int wid = threadIdx.x >> 6, lane = threadIdx.x & 63;
  int n = blockIdx.x * 4 + wid;
  float y[4];
  float m = 0.f;
#pragma unroll
  for (int j = 0; j < 4; j++) {
    int c = lane + 64 * j;
    float mu = cs[c] * (1.0f / NN);
    float var = cs2[c] * (1.0f / NN) - mu * mu;
    float xv = x[(size_t)n * HDD + c];
    y[j] = (xv - mu) * rsqrtf(var + 1e-5f) * bg[c] + bb[c];
    m += y[j];
  }
  for (int off = 32; off; off >>= 1) m += __shfl_down(m, off);
  m = __shfl(m, 0) * (1.0f / HDD);
  float var = 0.f;
#pragma unroll
  for (int j = 0; j < 4; j++) { float d = y[j] - m; var += d * d; }
  for (int off = 32; off; off >>= 1) var += __shfl_down(var, off);
  var = __shfl(var, 0) * (1.0f / HDD);
  float inv = rsqrtf(var + 1e-5f);
#pragma unroll
  for (int j = 0; j < 4; j++) {
    int c = lane + 64 * j;
    float z = (y[j] - m) * inv * lg[c] + lb[c];
    z = z > 0.f ? z : expm1f(z);
    out[(size_t)n * HDD + c] = f2b(z);
  }
}

extern "C" void kernel_launch(void* const* d_in, const int* in_sizes, int n_in,
                              void* d_out, int out_size, void* d_ws, size_t ws_size,
                              hipStream_t stream) {
  const float* X   = (const float*)d_in[0];
  const float* H   = (const float*)d_in[1];
  const float* W1  = (const float*)d_in[2];
  const float* W2  = (const float*)d_in[3];
  const float* W3  = (const float*)d_in[4];
  const float* imp = (const float*)d_in[5];
  const float* b3  = (const float*)d_in[8];
  const float* bng = (const float*)d_in[9];
  const float* bnb = (const float*)d_in[10];
  const float* lng = (const float*)d_in[11];
  const float* lnb = (const float*)d_in[12];
  const float* rel = (const float*)d_in[13];
  (void)in_sizes; (void)n_in; (void)out_size; (void)ws_size;

  char* w = (char*)d_ws;
  size_t off = 0;
  auto alloc = [&](size_t bytes) -> void* {
    void* p = w + off;
    off += (bytes + 255) & ~(size_t)255;
    return p;
  };
  float* dvs  = (float*)alloc((size_t)RR * NN * 4);
  float* de   = (float*)alloc((size_t)RR * EE * 4);
  float* cs   = (float*)alloc(2 * HDD * 4);
  unsigned long long* mask1 = (unsigned long long*)alloc((size_t)RR * NN * (EE / 64) * 8);  // 4MB
  unsigned long long* mask2 = (unsigned long long*)alloc((size_t)RR * EE * (NN / 64) * 8);  // 4MB
  unsigned short* bufP = (unsigned short*)alloc((size_t)16 * NN * HDD * 2);    // 32MB bf16 partials
  unsigned short* bufC = (unsigned short*)alloc((size_t)RR * EE * HDD * 2);    // 4MB
  unsigned short* bufD = (unsigned short*)alloc((size_t)RR * EE * HDD * 2);    // 4MB
  unsigned short* bufE = (unsigned short*)alloc((size_t)RR * EE * HDD * 2);    // 4MB
  float* convout = (float*)alloc((size_t)NN * HDD * 4);                        // 4MB
  unsigned short* Xb    = (unsigned short*)alloc((size_t)NN * HDD * 2);        // 2MB
  unsigned short* XdvT  = (unsigned short*)alloc((size_t)RR * FF * NN * 2);    // 4MB (later: ydvT)
  unsigned short* hwdvT = (unsigned short*)alloc((size_t)RR * HDD * NN * 2);   // 8MB
  unsigned short* W1catT = (unsigned short*)alloc((size_t)RR * FF * HDD * 2);
  unsigned short* W2T    = (unsigned short*)alloc((size_t)RR * HDD * HDD * 2);
  unsigned short* W3T    = (unsigned short*)alloc((size_t)RR * HDD * FF * 2);
  unsigned short* Z1T  = bufD;   // [256][RR*EE] 4MB
  unsigned short* bufE2 = bufE;  // [256][RR*EE] 4MB
  unsigned short* ydvT = XdvT;   // [r][128][NN] 4MB (XdvT dead by layer 3)
  unsigned short* bufC2 = bufC;  // [128][RR*EE] 2MB (bufC dead after G1.5)

  // ---- prep (2 dispatches) ----
  k_prep1<<<4096 + 2048 + 34, 256, 0, stream>>>(H, rel, W1, W2, W3, imp,
                                                dvs, mask1, W1catT, W2T, W3T, de, cs);
  k_prep2<<<256 + 512, 256, 0, stream>>>(mask1, mask2, de, X, dvs, XdvT);

  // ---- layer 1 (128 -> 256) ----
  // G1: raw1[r][e][f] = de2[r,e] * sum_n B2[r,e,n] XdvT[r,f,n]  M=2048,N=128,K=4096, z=(r,SK8), DECA mask2
  k_gemm3<1, 0><<<dim3(EE / 128, 1, RR * 8), 256, 0, stream>>>(
      nullptr, XdvT, NN, 8, 0, NN, 0, (long)FF * NN,
      bufP, (long)EE * FF, 8L * EE * FF, FF,
      mask2, NN / 64, EE, nullptr, nullptr, 0, de, nullptr, rel);
  k_red_b<<<dim3((EE * FF) / 2048, RR), 256, 0, stream>>>(bufP, bufC, 8, (long)EE * FF, nullptr);
  // G1.5: Z1T[o][r*EE+e] = sum_f W1catT[o][r*FF+f] bufC[r][e][f]  M=256,N=2048,K=128, z=r
  k_gemm3<0, 0><<<dim3(HDD / 128, EE / 128, RR), 256, 0, stream>>>(
      W1catT, bufC, FF, 1, RR * FF, FF, FF, (long)EE * FF,
      Z1T, 0, EE, RR * EE,
      nullptr, 0, 0, nullptr, nullptr, 0, nullptr, nullptr, nullptr);
  // G2: out1_part[kz][n][o] = sum_{re in kz} dv[r,n] B1[n,re] Z1T[o][re]  M=4096,N=256,K=8192 flat, SK=8
  k_gemm3<1, 1><<<dim3(NN / 128, HDD / 128, 8), 256, 0, stream>>>(
      nullptr, Z1T, RR * EE, 8, 0, RR * EE, 0, 0,
      bufP, (long)NN * HDD, 0, HDD,
      mask1, 0, 0, dvs, nullptr, 0, nullptr, nullptr, nullptr);
  k_redstats<<<NN / 32, 256, 0, stream>>>(bufP, convout, cs, cs + HDD, 8);
  k_bnlnelu<<<NN / 4, 256, 0, stream>>>(convout, cs, cs + HDD, bng, bnb, lng, lnb, Xb);

  // ---- layer 2 (256 -> 256), W2 applied first ----
  // hwdvT[r][o][n] = dv[r,n] * sum_c W2T[r,o,c] Xb[n,c]  M=256,N=4096,K=256, z=r
  k_gemm3<0, 0><<<dim3(HDD / 128, NN / 128, RR), 256, 0, stream>>>(
      W2T, Xb, HDD, 1, HDD, HDD, (long)HDD * HDD, 0,
      hwdvT, 0, (long)HDD * NN, NN,
      nullptr, 0, 0, nullptr, dvs, NN, nullptr, nullptr, nullptr);
  // L2-1: part[kz][o][r*EE+e] = de2[r,e] * sum_n B2[r,e,n] hwdvT[r,o,n]  M=256,N=2048,K=4096, z=(r,SK4), DECB mask2
  k_gemm3<2, 0><<<dim3(HDD / 128, EE / 128, RR * 4), 256, 0, stream>>>(
      hwdvT, nullptr, NN, 4, NN, 0, (long)HDD * NN, 0,
      bufP, (long)HDD * RR * EE, EE, RR * EE,
      mask2, NN / 64, EE, nullptr, nullptr, 0, nullptr, de, rel);
  k_red_b<<<dim3((HDD * RR * EE) / 2048, 1), 256, 0, stream>>>(
      bufP, bufE2, 4, (long)HDD * RR * EE, cs);
  // L2-2: out2_part[kz][n][o] = sum_{re} dv[r,n] B1[n,re] bufE2[o][re]  M=4096,N=256,K=8192 flat, SK=8
  k_gemm3<1, 1><<<dim3(NN / 128, HDD / 128, 8), 256, 0, stream>>>(
      nullptr, bufE2, RR * EE, 8, 0, RR * EE, 0, 0,
      bufP, (long)NN * HDD, 0, HDD,
      mask1, 0, 0, dvs, nullptr, 0, nullptr, nullptr, nullptr);
  k_redstats<<<NN / 32, 256, 0, stream>>>(bufP, convout, cs, cs + HDD, 8);
  k_bnlnelu<<<NN / 4, 256, 0, stream>>>(convout, cs, cs + HDD, bng + HDD, bnb + HDD, lng + HDD, lnb + HDD, Xb);

  // ---- layer 3 (256 -> 128), W3 applied first ----
  // ydvT[r][f][n] = dv[r,n] * sum_c W3T[r,f,c] Xb[n,c]  M=128,N=4096,K=256, z=r
  k_gemm3<0, 0><<<dim3(1, NN / 128, RR), 256, 0, stream>>>(
      W3T, Xb, HDD, 1, HDD, HDD, (long)FF * HDD, 0,
      ydvT, 0, (long)FF * NN, NN,
      nullptr, 0, 0, nullptr, dvs, NN, nullptr, nullptr, nullptr);
  // L3-1: part[kz][f][r*EE+e] = de2[r,e] * sum_n B2[r,e,n] ydvT[r,f,n]  M=128,N=2048,K=4096, z=(r,SK8), DECB mask2
  k_gemm3<2, 0><<<dim3(1, EE / 128, RR * 8), 256, 0, stream>>>(
      ydvT, nullptr, NN, 8, NN, 0, (long)FF * NN, 0,
      bufP, (long)FF * RR * EE, EE, RR * EE,
      mask2, NN / 64, EE, nullptr, nullptr, 0, nullptr, de, rel);
  k_red_b<<<dim3((FF * RR * EE) / 2048, 1), 256, 0, stream>>>(
      bufP, bufC2, 8, (long)FF * RR * EE, nullptr);
  // L3-2: out3_part[kz][n][f] = sum_{re} dv[r,n] B1[n,re] bufC2[f][re]  M=4096,N=128,K=8192 flat, SK=16
  k_gemm3<1, 1><<<dim3(NN / 128, 1, 16), 256, 0, stream>>>(
      nullptr, bufC2, RR * EE, 16, 0, RR * EE, 0, 0,
      bufP, (long)NN * FF, 0, FF,
      mask1, 0, 0, dvs, nullptr, 0, nullptr, nullptr, nullptr);
  // d_out = X + b3 + sum_z P[z]
  k_red_out<<<(NN * FF) / 1024, 256, 0, stream>>>(bufP, X, b3, (float*)d_out, 16);
}